// Round 1
// baseline (6027.967 us; speedup 1.0000x reference)
//
#include <hip/hip_runtime.h>

#define PW 65   // padded LDS row (2-way bank conflicts only — free)

__device__ __forceinline__ float silu_f(float v) {
    return v * (1.0f / (1.0f + __expf(-v)));
}

// ---------------------------------------------------------------------------
// Edge kernel: per edge e, cat = [ea[e], x[src], x[dst]] (192) -> silu(W1·cat+b1)
// -> W2·h+b2 -> ea_out[e]; atomicAdd into agg[dst].
// 1 wave per block, lane = edge. acc[64] in VGPRs; weights via uniform s_load.
// ---------------------------------------------------------------------------
__global__ __launch_bounds__(64) void gnn_edge_kernel(
    const float* __restrict__ x,
    const float* __restrict__ ea_in,
    float* __restrict__ ea_out,
    const int* __restrict__ src_idx,
    const int* __restrict__ dst_idx,
    const float* __restrict__ w1, const float* __restrict__ b1,
    const float* __restrict__ w2, const float* __restrict__ b2,
    float* __restrict__ agg,
    int E)
{
    __shared__ float seg[64][PW];
    const int lane = threadIdx.x;
    const long eBase = (long)blockIdx.x * 64;
    long e = eBase + lane;
    const bool valid = (e < E);
    if (e >= E) e = E - 1;
    const int s = src_idx[e];
    const int d = dst_idx[e];

    float acc[64];
#pragma unroll
    for (int c = 0; c < 64; ++c) acc[c] = b1[c];

    // ---- segment 0: own edge_attr rows (coalesced float4) ----
    for (int it = 0; it < 16; ++it) {
        int q  = it * 64 + lane;
        int r  = q >> 4;
        int c4 = (q & 15) << 2;
        long row = eBase + r; if (row >= E) row = E - 1;
        float4 v = *reinterpret_cast<const float4*>(ea_in + row * 64 + c4);
        seg[r][c4 + 0] = v.x; seg[r][c4 + 1] = v.y;
        seg[r][c4 + 2] = v.z; seg[r][c4 + 3] = v.w;
    }
    __syncthreads();
    for (int f = 0; f < 64; ++f) {
        float v = seg[lane][f];
        const float* wr = w1 + f * 64;            // wave-uniform -> s_load
#pragma unroll
        for (int c = 0; c < 64; ++c) acc[c] = fmaf(v, wr[c], acc[c]);
    }
    __syncthreads();

    // ---- segment 1: x[src] rows (gather, 256B rows, coalesced within row) ----
    for (int it = 0; it < 16; ++it) {
        int q  = it * 64 + lane;
        int r  = q >> 4;
        int c4 = (q & 15) << 2;
        int sr = __shfl(s, r);
        float4 v = *reinterpret_cast<const float4*>(x + (long)sr * 64 + c4);
        seg[r][c4 + 0] = v.x; seg[r][c4 + 1] = v.y;
        seg[r][c4 + 2] = v.z; seg[r][c4 + 3] = v.w;
    }
    __syncthreads();
    for (int f = 0; f < 64; ++f) {
        float v = seg[lane][f];
        const float* wr = w1 + (64 + f) * 64;
#pragma unroll
        for (int c = 0; c < 64; ++c) acc[c] = fmaf(v, wr[c], acc[c]);
    }
    __syncthreads();

    // ---- segment 2: x[dst] rows ----
    for (int it = 0; it < 16; ++it) {
        int q  = it * 64 + lane;
        int r  = q >> 4;
        int c4 = (q & 15) << 2;
        int dr = __shfl(d, r);
        float4 v = *reinterpret_cast<const float4*>(x + (long)dr * 64 + c4);
        seg[r][c4 + 0] = v.x; seg[r][c4 + 1] = v.y;
        seg[r][c4 + 2] = v.z; seg[r][c4 + 3] = v.w;
    }
    __syncthreads();
    for (int f = 0; f < 64; ++f) {
        float v = seg[lane][f];
        const float* wr = w1 + (128 + f) * 64;
#pragma unroll
        for (int c = 0; c < 64; ++c) acc[c] = fmaf(v, wr[c], acc[c]);
    }
    __syncthreads();

    // ---- silu, stage h, second linear ----
#pragma unroll
    for (int c = 0; c < 64; ++c) seg[lane][c] = silu_f(acc[c]);
    __syncthreads();
#pragma unroll
    for (int c = 0; c < 64; ++c) acc[c] = b2[c];
    for (int k = 0; k < 64; ++k) {
        float v = seg[lane][k];
        const float* wr = w2 + k * 64;
#pragma unroll
        for (int c = 0; c < 64; ++c) acc[c] = fmaf(v, wr[c], acc[c]);
    }
    __syncthreads();

    // ---- scatter-add to agg[dst] ----
    if (valid) {
        const long db = (long)d * 64;
#pragma unroll
        for (int c = 0; c < 64; ++c) atomicAdd(&agg[db + c], acc[c]);
    }

    // ---- stage + coalesced writeback of ea_out ----
#pragma unroll
    for (int c = 0; c < 64; ++c) seg[lane][c] = acc[c];
    __syncthreads();
    for (int it = 0; it < 16; ++it) {
        int q  = it * 64 + lane;
        int r  = q >> 4;
        int c4 = (q & 15) << 2;
        long row = eBase + r;
        if (row < E) {
            float4 v;
            v.x = seg[r][c4 + 0]; v.y = seg[r][c4 + 1];
            v.z = seg[r][c4 + 2]; v.w = seg[r][c4 + 3];
            *reinterpret_cast<float4*>(ea_out + row * 64 + c4) = v;
        }
    }
}

// ---------------------------------------------------------------------------
// Node kernel: per node n, cat = [x[n], agg[n]] (128) -> silu(W1·cat+b1)
// -> W2·h+b2 -> x_out[n]. Same structure, no atomics.
// ---------------------------------------------------------------------------
__global__ __launch_bounds__(64) void gnn_node_kernel(
    const float* __restrict__ x_in,
    const float* __restrict__ agg,
    float* __restrict__ x_out,
    const float* __restrict__ w1, const float* __restrict__ b1,
    const float* __restrict__ w2, const float* __restrict__ b2,
    int N)
{
    __shared__ float seg[64][PW];
    const int lane = threadIdx.x;
    const long nBase = (long)blockIdx.x * 64;
    const long n = nBase + lane;
    const bool valid = (n < N);

    float acc[64];
#pragma unroll
    for (int c = 0; c < 64; ++c) acc[c] = b1[c];

    // ---- segment 0: own x rows ----
    for (int it = 0; it < 16; ++it) {
        int q  = it * 64 + lane;
        int r  = q >> 4;
        int c4 = (q & 15) << 2;
        long row = nBase + r; if (row >= N) row = N - 1;
        float4 v = *reinterpret_cast<const float4*>(x_in + row * 64 + c4);
        seg[r][c4 + 0] = v.x; seg[r][c4 + 1] = v.y;
        seg[r][c4 + 2] = v.z; seg[r][c4 + 3] = v.w;
    }
    __syncthreads();
    for (int f = 0; f < 64; ++f) {
        float v = seg[lane][f];
        const float* wr = w1 + f * 64;
#pragma unroll
        for (int c = 0; c < 64; ++c) acc[c] = fmaf(v, wr[c], acc[c]);
    }
    __syncthreads();

    // ---- segment 1: own agg rows ----
    for (int it = 0; it < 16; ++it) {
        int q  = it * 64 + lane;
        int r  = q >> 4;
        int c4 = (q & 15) << 2;
        long row = nBase + r; if (row >= N) row = N - 1;
        float4 v = *reinterpret_cast<const float4*>(agg + row * 64 + c4);
        seg[r][c4 + 0] = v.x; seg[r][c4 + 1] = v.y;
        seg[r][c4 + 2] = v.z; seg[r][c4 + 3] = v.w;
    }
    __syncthreads();
    for (int f = 0; f < 64; ++f) {
        float v = seg[lane][f];
        const float* wr = w1 + (64 + f) * 64;
#pragma unroll
        for (int c = 0; c < 64; ++c) acc[c] = fmaf(v, wr[c], acc[c]);
    }
    __syncthreads();

    // ---- silu, stage h, second linear ----
#pragma unroll
    for (int c = 0; c < 64; ++c) seg[lane][c] = silu_f(acc[c]);
    __syncthreads();
#pragma unroll
    for (int c = 0; c < 64; ++c) acc[c] = b2[c];
    for (int k = 0; k < 64; ++k) {
        float v = seg[lane][k];
        const float* wr = w2 + k * 64;
#pragma unroll
        for (int c = 0; c < 64; ++c) acc[c] = fmaf(v, wr[c], acc[c]);
    }
    __syncthreads();

    // ---- stage + coalesced writeback of x_out ----
#pragma unroll
    for (int c = 0; c < 64; ++c) seg[lane][c] = acc[c];
    __syncthreads();
    for (int it = 0; it < 16; ++it) {
        int q  = it * 64 + lane;
        int r  = q >> 4;
        int c4 = (q & 15) << 2;
        long row = nBase + r;
        if (row < N) {
            float4 v;
            v.x = seg[r][c4 + 0]; v.y = seg[r][c4 + 1];
            v.z = seg[r][c4 + 2]; v.w = seg[r][c4 + 3];
            *reinterpret_cast<float4*>(x_out + row * 64 + c4) = v;
        }
    }
}

extern "C" void kernel_launch(void* const* d_in, const int* in_sizes, int n_in,
                              void* d_out, int out_size, void* d_ws, size_t ws_size,
                              hipStream_t stream) {
    const int H = 64;
    const int N = in_sizes[0] / H;   // 50000
    const int E = in_sizes[1] / H;   // 800000

    const float* x0  = (const float*)d_in[0];
    const float* ea0 = (const float*)d_in[1];
    const int*   ei  = (const int*)d_in[2];
    const float* ew1 = (const float*)d_in[3];
    const float* eb1 = (const float*)d_in[4];
    const float* ew2 = (const float*)d_in[5];
    const float* eb2 = (const float*)d_in[6];
    const float* nw1 = (const float*)d_in[7];
    const float* nb1 = (const float*)d_in[8];
    const float* nw2 = (const float*)d_in[9];
    const float* nb2 = (const float*)d_in[10];

    float* outX = (float*)d_out;                 // [N, H]
    float* outE = outX + (size_t)N * H;          // [E, H]
    float* agg  = (float*)d_ws;                  // [N, H]

    const int* srcI = ei;
    const int* dstI = ei + E;

    const int egrid = (E + 63) / 64;
    const int ngrid = (N + 63) / 64;
    const size_t aggBytes = (size_t)N * H * sizeof(float);

    for (int l = 0; l < 2; ++l) {
        const float* xin  = (l == 0) ? x0  : outX;
        const float* eain = (l == 0) ? ea0 : outE;
        hipMemsetAsync(agg, 0, aggBytes, stream);
        gnn_edge_kernel<<<egrid, 64, 0, stream>>>(
            xin, eain, outE, srcI, dstI,
            ew1 + (size_t)l * 3 * H * H, eb1 + l * H,
            ew2 + (size_t)l * H * H,     eb2 + l * H,
            agg, E);
        gnn_node_kernel<<<ngrid, 64, 0, stream>>>(
            xin, agg, outX,
            nw1 + (size_t)l * 2 * H * H, nb1 + l * H,
            nw2 + (size_t)l * H * H,     nb2 + l * H,
            N);
    }
}

// Round 2
// 941.138 us; speedup vs baseline: 6.4050x; 6.4050x over previous
//
#include <hip/hip_runtime.h>

#define PW 65   // padded LDS row: bank = (lane*65+f)%32 = (lane+f)%32 -> 2-way only (free)

__device__ __forceinline__ float silu_f(float v) {
    return v * (1.0f / (1.0f + __expf(-v)));
}

// ---------------------------------------------------------------------------
// Edge kernel: 256 threads (4 waves) per 64-edge tile.
// Wave w computes output channels [16w,16w+16) for all 64 edges (lane = edge).
// Weights are wave-uniform (readfirstlane'd wave id) -> s_load_dwordx16.
// Scatter-add is transposed: lane = channel, one dst row per instruction.
// ---------------------------------------------------------------------------
__global__ __launch_bounds__(256, 8) void gnn_edge_kernel(
    const float* __restrict__ x,
    const float* __restrict__ ea_in,
    float* __restrict__ ea_out,
    const int* __restrict__ src_idx,
    const int* __restrict__ dst_idx,
    const float* __restrict__ w1, const float* __restrict__ b1,
    const float* __restrict__ w2, const float* __restrict__ b2,
    float* __restrict__ agg,
    int E)
{
    __shared__ float seg[64][PW];
    __shared__ int dsts_s[64];
    __shared__ int srcs_s[64];

    const int t     = threadIdx.x;
    const int lane  = t & 63;
    const int w     = __builtin_amdgcn_readfirstlane(t >> 6);  // force SGPR
    const int cbase = w * 16;
    const long base = (long)blockIdx.x * 64;

    if (t < 64) {
        long e = base + t; if (e >= E) e = E - 1;
        srcs_s[t] = src_idx[e];
        dsts_s[t] = dst_idx[e];
    }

    float acc[16];
#pragma unroll
    for (int j = 0; j < 16; ++j) acc[j] = b1[cbase + j];

    // ---- segment 0: edge_attr rows (coalesced float4, block-wide staging) ----
#pragma unroll
    for (int it = 0; it < 4; ++it) {
        int q = it * 256 + t;
        int r = q >> 4, c4 = (q & 15) << 2;
        long row = base + r; if (row >= E) row = E - 1;
        float4 v = *reinterpret_cast<const float4*>(ea_in + row * 64 + c4);
        seg[r][c4 + 0] = v.x; seg[r][c4 + 1] = v.y;
        seg[r][c4 + 2] = v.z; seg[r][c4 + 3] = v.w;
    }
    __syncthreads();
    for (int f = 0; f < 64; ++f) {
        float v = seg[lane][f];
        const float* wr = w1 + f * 64 + cbase;          // uniform -> s_load_dwordx16
#pragma unroll
        for (int j = 0; j < 16; ++j) acc[j] = fmaf(v, wr[j], acc[j]);
    }
    __syncthreads();

    // ---- segment 1: x[src] rows (gather) ----
#pragma unroll
    for (int it = 0; it < 4; ++it) {
        int q = it * 256 + t;
        int r = q >> 4, c4 = (q & 15) << 2;
        int sr = srcs_s[r];
        float4 v = *reinterpret_cast<const float4*>(x + (long)sr * 64 + c4);
        seg[r][c4 + 0] = v.x; seg[r][c4 + 1] = v.y;
        seg[r][c4 + 2] = v.z; seg[r][c4 + 3] = v.w;
    }
    __syncthreads();
    for (int f = 0; f < 64; ++f) {
        float v = seg[lane][f];
        const float* wr = w1 + (64 + f) * 64 + cbase;
#pragma unroll
        for (int j = 0; j < 16; ++j) acc[j] = fmaf(v, wr[j], acc[j]);
    }
    __syncthreads();

    // ---- segment 2: x[dst] rows (gather) ----
#pragma unroll
    for (int it = 0; it < 4; ++it) {
        int q = it * 256 + t;
        int r = q >> 4, c4 = (q & 15) << 2;
        int dr = dsts_s[r];
        float4 v = *reinterpret_cast<const float4*>(x + (long)dr * 64 + c4);
        seg[r][c4 + 0] = v.x; seg[r][c4 + 1] = v.y;
        seg[r][c4 + 2] = v.z; seg[r][c4 + 3] = v.w;
    }
    __syncthreads();
    for (int f = 0; f < 64; ++f) {
        float v = seg[lane][f];
        const float* wr = w1 + (128 + f) * 64 + cbase;
#pragma unroll
        for (int j = 0; j < 16; ++j) acc[j] = fmaf(v, wr[j], acc[j]);
    }
    __syncthreads();

    // ---- silu -> stage h (each wave writes its 16 columns of its lane's row) ----
#pragma unroll
    for (int j = 0; j < 16; ++j) seg[lane][cbase + j] = silu_f(acc[j]);
    __syncthreads();

    // ---- second linear ----
#pragma unroll
    for (int j = 0; j < 16; ++j) acc[j] = b2[cbase + j];
    for (int k = 0; k < 64; ++k) {
        float v = seg[lane][k];
        const float* wr = w2 + k * 64 + cbase;
#pragma unroll
        for (int j = 0; j < 16; ++j) acc[j] = fmaf(v, wr[j], acc[j]);
    }
    __syncthreads();   // all reads of h done before overwrite

    // ---- stage output tile ----
#pragma unroll
    for (int j = 0; j < 16; ++j) seg[lane][cbase + j] = acc[j];
    __syncthreads();

    // ---- coalesced writeback of ea_out (block-wide float4) ----
#pragma unroll
    for (int it = 0; it < 4; ++it) {
        int q = it * 256 + t;
        int r = q >> 4, c4 = (q & 15) << 2;
        long row = base + r;
        if (row < E) {
            float4 v;
            v.x = seg[r][c4 + 0]; v.y = seg[r][c4 + 1];
            v.z = seg[r][c4 + 2]; v.w = seg[r][c4 + 3];
            *reinterpret_cast<float4*>(ea_out + row * 64 + c4) = v;
        }
    }

    // ---- transposed scatter: lane = channel, one dst row per instruction ----
    // Each instruction: 64 lanes write 64 consecutive dwords of agg[d] -> 4 lines.
#pragma unroll
    for (int j = 0; j < 16; ++j) {
        int r = w * 16 + j;
        long row = base + r;
        if (row < E) {
            float val = seg[r][lane];                 // bank (r+lane)%32: 2-way, free
            atomicAdd(&agg[(long)dsts_s[r] * 64 + lane], val);
        }
    }
}

// ---------------------------------------------------------------------------
// Node kernel: 256 threads per 64-node tile; wave w -> channels [16w,16w+16).
// cat = [x[n], agg[n]] (128) -> silu(W1·cat+b1) -> W2·h+b2 -> x_out[n].
// ---------------------------------------------------------------------------
__global__ __launch_bounds__(256, 8) void gnn_node_kernel(
    const float* __restrict__ x_in,
    const float* __restrict__ agg,
    float* __restrict__ x_out,
    const float* __restrict__ w1, const float* __restrict__ b1,
    const float* __restrict__ w2, const float* __restrict__ b2,
    int N)
{
    __shared__ float seg[64][PW];

    const int t     = threadIdx.x;
    const int lane  = t & 63;
    const int w     = __builtin_amdgcn_readfirstlane(t >> 6);
    const int cbase = w * 16;
    const long base = (long)blockIdx.x * 64;

    float acc[16];
#pragma unroll
    for (int j = 0; j < 16; ++j) acc[j] = b1[cbase + j];

    // ---- segment 0: x rows ----
#pragma unroll
    for (int it = 0; it < 4; ++it) {
        int q = it * 256 + t;
        int r = q >> 4, c4 = (q & 15) << 2;
        long row = base + r; if (row >= N) row = N - 1;
        float4 v = *reinterpret_cast<const float4*>(x_in + row * 64 + c4);
        seg[r][c4 + 0] = v.x; seg[r][c4 + 1] = v.y;
        seg[r][c4 + 2] = v.z; seg[r][c4 + 3] = v.w;
    }
    __syncthreads();
    for (int f = 0; f < 64; ++f) {
        float v = seg[lane][f];
        const float* wr = w1 + f * 64 + cbase;
#pragma unroll
        for (int j = 0; j < 16; ++j) acc[j] = fmaf(v, wr[j], acc[j]);
    }
    __syncthreads();

    // ---- segment 1: agg rows ----
#pragma unroll
    for (int it = 0; it < 4; ++it) {
        int q = it * 256 + t;
        int r = q >> 4, c4 = (q & 15) << 2;
        long row = base + r; if (row >= N) row = N - 1;
        float4 v = *reinterpret_cast<const float4*>(agg + row * 64 + c4);
        seg[r][c4 + 0] = v.x; seg[r][c4 + 1] = v.y;
        seg[r][c4 + 2] = v.z; seg[r][c4 + 3] = v.w;
    }
    __syncthreads();
    for (int f = 0; f < 64; ++f) {
        float v = seg[lane][f];
        const float* wr = w1 + (64 + f) * 64 + cbase;
#pragma unroll
        for (int j = 0; j < 16; ++j) acc[j] = fmaf(v, wr[j], acc[j]);
    }
    __syncthreads();

    // ---- silu -> stage h ----
#pragma unroll
    for (int j = 0; j < 16; ++j) seg[lane][cbase + j] = silu_f(acc[j]);
    __syncthreads();

    // ---- second linear ----
#pragma unroll
    for (int j = 0; j < 16; ++j) acc[j] = b2[cbase + j];
    for (int k = 0; k < 64; ++k) {
        float v = seg[lane][k];
        const float* wr = w2 + k * 64 + cbase;
#pragma unroll
        for (int j = 0; j < 16; ++j) acc[j] = fmaf(v, wr[j], acc[j]);
    }
    __syncthreads();

    // ---- stage output tile ----
#pragma unroll
    for (int j = 0; j < 16; ++j) seg[lane][cbase + j] = acc[j];
    __syncthreads();

    // ---- coalesced writeback ----
#pragma unroll
    for (int it = 0; it < 4; ++it) {
        int q = it * 256 + t;
        int r = q >> 4, c4 = (q & 15) << 2;
        long row = base + r;
        if (row < N) {
            float4 v;
            v.x = seg[r][c4 + 0]; v.y = seg[r][c4 + 1];
            v.z = seg[r][c4 + 2]; v.w = seg[r][c4 + 3];
            *reinterpret_cast<float4*>(x_out + row * 64 + c4) = v;
        }
    }
}

extern "C" void kernel_launch(void* const* d_in, const int* in_sizes, int n_in,
                              void* d_out, int out_size, void* d_ws, size_t ws_size,
                              hipStream_t stream) {
    const int H = 64;
    const int N = in_sizes[0] / H;   // 50000
    const int E = in_sizes[1] / H;   // 800000

    const float* x0  = (const float*)d_in[0];
    const float* ea0 = (const float*)d_in[1];
    const int*   ei  = (const int*)d_in[2];
    const float* ew1 = (const float*)d_in[3];
    const float* eb1 = (const float*)d_in[4];
    const float* ew2 = (const float*)d_in[5];
    const float* eb2 = (const float*)d_in[6];
    const float* nw1 = (const float*)d_in[7];
    const float* nb1 = (const float*)d_in[8];
    const float* nw2 = (const float*)d_in[9];
    const float* nb2 = (const float*)d_in[10];

    float* outX = (float*)d_out;                 // [N, H]
    float* outE = outX + (size_t)N * H;          // [E, H]
    float* agg  = (float*)d_ws;                  // [N, H]

    const int* srcI = ei;
    const int* dstI = ei + E;

    const int egrid = (E + 63) / 64;
    const int ngrid = (N + 63) / 64;
    const size_t aggBytes = (size_t)N * H * sizeof(float);

    for (int l = 0; l < 2; ++l) {
        const float* xin  = (l == 0) ? x0  : outX;
        const float* eain = (l == 0) ? ea0 : outE;
        hipMemsetAsync(agg, 0, aggBytes, stream);
        gnn_edge_kernel<<<egrid, 256, 0, stream>>>(
            xin, eain, outE, srcI, dstI,
            ew1 + (size_t)l * 3 * H * H, eb1 + l * H,
            ew2 + (size_t)l * H * H,     eb2 + l * H,
            agg, E);
        gnn_node_kernel<<<ngrid, 256, 0, stream>>>(
            xin, agg, outX,
            nw1 + (size_t)l * 2 * H * H, nb1 + l * H,
            nw2 + (size_t)l * H * H,     nb2 + l * H,
            N);
    }
}

// Round 3
// 594.581 us; speedup vs baseline: 10.1382x; 1.5829x over previous
//
#include <hip/hip_runtime.h>

typedef __attribute__((ext_vector_type(8))) short bf16x8;
typedef __attribute__((ext_vector_type(4))) float f32x4;

#define PWS 72   // short-pitch of LDS tiles: row stride 144B (16B-aligned, conflict-benign)

__device__ __forceinline__ float silu_f(float v) {
    return v * (1.0f / (1.0f + __expf(-v)));
}

// split f32 into hi (bf16 truncation, exact residual) + lo (bf16 of residual)
// combined representation error ~2^-17 relative.
__device__ __forceinline__ void split_bf(float f, short& h, short& l) {
    unsigned u = __float_as_uint(f);
    h = (short)(u >> 16);
    float res = f - __uint_as_float(u & 0xffff0000u);   // exact
    l = (short)(__float_as_uint(res) >> 16);
}

// ---------------------------------------------------------------------------
// Weight pre-conversion: fp32 [K][64] -> hi/lo bf16 in B-fragment order:
//   out[((t*4+nf)*64 + lane)*8 + j] = W[t*32 + (lane>>4)*8 + j][nf*16 + (lane&15)]
// so the GEMM loop's B-load is one coalesced 16B load per lane.
// ---------------------------------------------------------------------------
struct WDesc { const float* W; short* hi; short* lo; int K; };
struct WPack { WDesc d[8]; };

__global__ __launch_bounds__(256) void conv_weights(WPack p) {
    WDesc wd = p.d[blockIdx.y];
    int total = wd.K * 64;
    int i = blockIdx.x * 256 + threadIdx.x;
    if (i >= total) return;
    int j  = i & 7;
    int l  = (i >> 3) & 63;
    int tn = i >> 9;                 // t*4 + nf
    int t  = tn >> 2, nf = tn & 3;
    int k  = t * 32 + (l >> 4) * 8 + j;
    int c  = nf * 16 + (l & 15);
    float f = wd.W[k * 64 + c];
    unsigned u = __float_as_uint(f);
    short h = (short)(u >> 16);                                  // truncate
    float res = f - __uint_as_float(u & 0xffff0000u);            // exact residual
    unsigned ur = __float_as_uint(res);
    short lo16 = (short)((ur + 0x7fffu + ((ur >> 16) & 1u)) >> 16);  // RNE
    wd.hi[i] = h;
    wd.lo[i] = lo16;
}

// ---------------------------------------------------------------------------
// Edge kernel: 256 threads = 4 independent waves, each owns 16 edges.
// Per wave: A-tile = 16 edges x 192 feats (staged per-wave in LDS as hi/lo bf16),
// C = 16x64 via 4 n-frags of mfma_f32_16x16x32_bf16, 3-pass split-bf16.
// No __syncthreads anywhere (waves touch disjoint LDS rows).
// ---------------------------------------------------------------------------
__global__ __launch_bounds__(256, 4) void gnn_edge_mfma(
    const float* __restrict__ x,
    const float* __restrict__ ea_in,
    float* __restrict__ ea_out,
    const int* __restrict__ src_idx,
    const int* __restrict__ dst_idx,
    const short* __restrict__ w1h, const short* __restrict__ w1l,
    const float* __restrict__ b1,
    const short* __restrict__ w2h, const short* __restrict__ w2l,
    const float* __restrict__ b2,
    float* __restrict__ agg, int E)
{
    __shared__ __align__(16) short seg_hi[64][PWS];
    __shared__ __align__(16) short seg_lo[64][PWS];

    const int t    = threadIdx.x;
    const int lane = t & 63;
    const int w    = t >> 6;
    const long base = (long)blockIdx.x * 64;
    const int col  = lane & 15;
    const int g    = lane >> 4;            // 0..3
    const int arow = w * 16 + col;         // A-operand row for this lane
    const int kg   = g * 8;

    f32x4 acc[4];
#pragma unroll
    for (int nf = 0; nf < 4; ++nf) {
        float bv = b1[nf * 16 + col];
        acc[nf] = (f32x4){bv, bv, bv, bv};
    }

    // ---- layer-1 GEMM over 3 concatenated segments (ea, x[src], x[dst]) ----
    for (int s3 = 0; s3 < 3; ++s3) {
        // per-wave staging of its 16 rows, with split-bf16 conversion
#pragma unroll
        for (int it = 0; it < 4; ++it) {
            int q  = it * 64 + lane;
            int rl = q >> 4;                    // 0..15
            int rg = w * 16 + rl;
            int c4 = (q & 15) << 2;
            long erow = base + rg; if (erow >= E) erow = E - 1;
            const float* sp;
            if      (s3 == 0) sp = ea_in + erow * 64 + c4;
            else if (s3 == 1) sp = x + (long)src_idx[erow] * 64 + c4;
            else              sp = x + (long)dst_idx[erow] * 64 + c4;
            float4 v = *(const float4*)sp;
            short h0,l0,h1,l1,h2,l2,h3,l3;
            split_bf(v.x, h0, l0); split_bf(v.y, h1, l1);
            split_bf(v.z, h2, l2); split_bf(v.w, h3, l3);
            *(short4*)&seg_hi[rg][c4] = make_short4(h0, h1, h2, h3);
            *(short4*)&seg_lo[rg][c4] = make_short4(l0, l1, l2, l3);
        }
#pragma unroll
        for (int tt = 0; tt < 2; ++tt) {
            int k0 = tt * 32 + kg;
            bf16x8 ahi = *(const bf16x8*)&seg_hi[arow][k0];
            bf16x8 alo = *(const bf16x8*)&seg_lo[arow][k0];
            int tg = s3 * 2 + tt;
#pragma unroll
            for (int nf = 0; nf < 4; ++nf) {
                bf16x8 bh = *(const bf16x8*)(w1h + (size_t)((tg * 4 + nf) * 64 + lane) * 8);
                bf16x8 bl = *(const bf16x8*)(w1l + (size_t)((tg * 4 + nf) * 64 + lane) * 8);
                acc[nf] = __builtin_amdgcn_mfma_f32_16x16x32_bf16(ahi, bh, acc[nf], 0, 0, 0);
                acc[nf] = __builtin_amdgcn_mfma_f32_16x16x32_bf16(ahi, bl, acc[nf], 0, 0, 0);
                acc[nf] = __builtin_amdgcn_mfma_f32_16x16x32_bf16(alo, bh, acc[nf], 0, 0, 0);
            }
        }
    }

    // ---- silu -> h staged back into the wave's own LDS rows (C-frag layout) ----
#pragma unroll
    for (int nf = 0; nf < 4; ++nf)
#pragma unroll
        for (int rg = 0; rg < 4; ++rg) {
            int row = w * 16 + g * 4 + rg;
            short hh, hl;
            split_bf(silu_f(acc[nf][rg]), hh, hl);
            seg_hi[row][nf * 16 + col] = hh;
            seg_lo[row][nf * 16 + col] = hl;
        }

    // ---- layer-2 GEMM (K=64) ----
    f32x4 out[4];
#pragma unroll
    for (int nf = 0; nf < 4; ++nf) {
        float bv = b2[nf * 16 + col];
        out[nf] = (f32x4){bv, bv, bv, bv};
    }
#pragma unroll
    for (int tt = 0; tt < 2; ++tt) {
        int k0 = tt * 32 + kg;
        bf16x8 ahi = *(const bf16x8*)&seg_hi[arow][k0];
        bf16x8 alo = *(const bf16x8*)&seg_lo[arow][k0];
#pragma unroll
        for (int nf = 0; nf < 4; ++nf) {
            bf16x8 bh = *(const bf16x8*)(w2h + (size_t)((tt * 4 + nf) * 64 + lane) * 8);
            bf16x8 bl = *(const bf16x8*)(w2l + (size_t)((tt * 4 + nf) * 64 + lane) * 8);
            out[nf] = __builtin_amdgcn_mfma_f32_16x16x32_bf16(ahi, bh, out[nf], 0, 0, 0);
            out[nf] = __builtin_amdgcn_mfma_f32_16x16x32_bf16(ahi, bl, out[nf], 0, 0, 0);
            out[nf] = __builtin_amdgcn_mfma_f32_16x16x32_bf16(alo, bh, out[nf], 0, 0, 0);
        }
    }

    // ---- epilogue: direct stores + transposed atomic scatter (64B/16-lane groups) ----
    const int rbase = w * 16 + g * 4;
#pragma unroll
    for (int rg = 0; rg < 4; ++rg) {
        long row = base + rbase + rg;
        if (row < E) {
            int d = dst_idx[row];
            float* op = ea_out + row * 64;
            float* ap = agg + (long)d * 64;
#pragma unroll
            for (int nf = 0; nf < 4; ++nf) {
                op[nf * 16 + col] = out[nf][rg];
                atomicAdd(&ap[nf * 16 + col], out[nf][rg]);
            }
        }
    }
}

// ---------------------------------------------------------------------------
// Node kernel: same structure, K = 128 (x then agg), no atomics.
// ---------------------------------------------------------------------------
__global__ __launch_bounds__(256, 4) void gnn_node_mfma(
    const float* __restrict__ x_in,
    const float* __restrict__ aggp,
    float* __restrict__ x_out,
    const short* __restrict__ w1h, const short* __restrict__ w1l,
    const float* __restrict__ b1,
    const short* __restrict__ w2h, const short* __restrict__ w2l,
    const float* __restrict__ b2, int N)
{
    __shared__ __align__(16) short seg_hi[64][PWS];
    __shared__ __align__(16) short seg_lo[64][PWS];

    const int t    = threadIdx.x;
    const int lane = t & 63;
    const int w    = t >> 6;
    const long base = (long)blockIdx.x * 64;
    const int col  = lane & 15;
    const int g    = lane >> 4;
    const int arow = w * 16 + col;
    const int kg   = g * 8;

    f32x4 acc[4];
#pragma unroll
    for (int nf = 0; nf < 4; ++nf) {
        float bv = b1[nf * 16 + col];
        acc[nf] = (f32x4){bv, bv, bv, bv};
    }

    for (int s2 = 0; s2 < 2; ++s2) {
#pragma unroll
        for (int it = 0; it < 4; ++it) {
            int q  = it * 64 + lane;
            int rl = q >> 4;
            int rg = w * 16 + rl;
            int c4 = (q & 15) << 2;
            long nrow = base + rg; if (nrow >= N) nrow = N - 1;
            const float* sp = (s2 == 0) ? (x_in + nrow * 64 + c4)
                                        : (aggp + nrow * 64 + c4);
            float4 v = *(const float4*)sp;
            short h0,l0,h1,l1,h2,l2,h3,l3;
            split_bf(v.x, h0, l0); split_bf(v.y, h1, l1);
            split_bf(v.z, h2, l2); split_bf(v.w, h3, l3);
            *(short4*)&seg_hi[rg][c4] = make_short4(h0, h1, h2, h3);
            *(short4*)&seg_lo[rg][c4] = make_short4(l0, l1, l2, l3);
        }
#pragma unroll
        for (int tt = 0; tt < 2; ++tt) {
            int k0 = tt * 32 + kg;
            bf16x8 ahi = *(const bf16x8*)&seg_hi[arow][k0];
            bf16x8 alo = *(const bf16x8*)&seg_lo[arow][k0];
            int tg = s2 * 2 + tt;
#pragma unroll
            for (int nf = 0; nf < 4; ++nf) {
                bf16x8 bh = *(const bf16x8*)(w1h + (size_t)((tg * 4 + nf) * 64 + lane) * 8);
                bf16x8 bl = *(const bf16x8*)(w1l + (size_t)((tg * 4 + nf) * 64 + lane) * 8);
                acc[nf] = __builtin_amdgcn_mfma_f32_16x16x32_bf16(ahi, bh, acc[nf], 0, 0, 0);
                acc[nf] = __builtin_amdgcn_mfma_f32_16x16x32_bf16(ahi, bl, acc[nf], 0, 0, 0);
                acc[nf] = __builtin_amdgcn_mfma_f32_16x16x32_bf16(alo, bh, acc[nf], 0, 0, 0);
            }
        }
    }

#pragma unroll
    for (int nf = 0; nf < 4; ++nf)
#pragma unroll
        for (int rg = 0; rg < 4; ++rg) {
            int row = w * 16 + g * 4 + rg;
            short hh, hl;
            split_bf(silu_f(acc[nf][rg]), hh, hl);
            seg_hi[row][nf * 16 + col] = hh;
            seg_lo[row][nf * 16 + col] = hl;
        }

    f32x4 out[4];
#pragma unroll
    for (int nf = 0; nf < 4; ++nf) {
        float bv = b2[nf * 16 + col];
        out[nf] = (f32x4){bv, bv, bv, bv};
    }
#pragma unroll
    for (int tt = 0; tt < 2; ++tt) {
        int k0 = tt * 32 + kg;
        bf16x8 ahi = *(const bf16x8*)&seg_hi[arow][k0];
        bf16x8 alo = *(const bf16x8*)&seg_lo[arow][k0];
#pragma unroll
        for (int nf = 0; nf < 4; ++nf) {
            bf16x8 bh = *(const bf16x8*)(w2h + (size_t)((tt * 4 + nf) * 64 + lane) * 8);
            bf16x8 bl = *(const bf16x8*)(w2l + (size_t)((tt * 4 + nf) * 64 + lane) * 8);
            out[nf] = __builtin_amdgcn_mfma_f32_16x16x32_bf16(ahi, bh, out[nf], 0, 0, 0);
            out[nf] = __builtin_amdgcn_mfma_f32_16x16x32_bf16(ahi, bl, out[nf], 0, 0, 0);
            out[nf] = __builtin_amdgcn_mfma_f32_16x16x32_bf16(alo, bh, out[nf], 0, 0, 0);
        }
    }

    const int rbase = w * 16 + g * 4;
#pragma unroll
    for (int rg = 0; rg < 4; ++rg) {
        long row = base + rbase + rg;
        if (row < N) {
            float* op = x_out + row * 64;
#pragma unroll
            for (int nf = 0; nf < 4; ++nf)
                op[nf * 16 + col] = out[nf][rg];
        }
    }
}

extern "C" void kernel_launch(void* const* d_in, const int* in_sizes, int n_in,
                              void* d_out, int out_size, void* d_ws, size_t ws_size,
                              hipStream_t stream) {
    const int H = 64;
    const int N = in_sizes[0] / H;   // 50000
    const int E = in_sizes[1] / H;   // 800000

    const float* x0  = (const float*)d_in[0];
    const float* ea0 = (const float*)d_in[1];
    const int*   ei  = (const int*)d_in[2];
    const float* ew1 = (const float*)d_in[3];
    const float* eb1 = (const float*)d_in[4];
    const float* ew2 = (const float*)d_in[5];
    const float* eb2 = (const float*)d_in[6];
    const float* nw1 = (const float*)d_in[7];
    const float* nb1 = (const float*)d_in[8];
    const float* nw2 = (const float*)d_in[9];
    const float* nb2 = (const float*)d_in[10];

    float* outX = (float*)d_out;                 // [N, H]
    float* outE = outX + (size_t)N * H;          // [E, H]
    float* agg  = (float*)d_ws;                  // [N, H] fp32
    short* wbase = (short*)((char*)d_ws + (size_t)N * H * sizeof(float));

    const int* srcI = ei;
    const int* dstI = ei + E;

    // carve weight-fragment buffers and build the conversion pack
    WPack pack;
    size_t off = 0;
    short* EH[2]; short* EL[2]; short* E2H[2]; short* E2L[2];
    short* NH[2]; short* NL[2]; short* N2H[2]; short* N2L[2];
    for (int l = 0; l < 2; ++l) {
        EH[l]  = wbase + off; off += 192 * 64;
        EL[l]  = wbase + off; off += 192 * 64;
        E2H[l] = wbase + off; off += 64 * 64;
        E2L[l] = wbase + off; off += 64 * 64;
        NH[l]  = wbase + off; off += 128 * 64;
        NL[l]  = wbase + off; off += 128 * 64;
        N2H[l] = wbase + off; off += 64 * 64;
        N2L[l] = wbase + off; off += 64 * 64;
        pack.d[l * 4 + 0] = {ew1 + (size_t)l * 192 * 64, EH[l],  EL[l],  192};
        pack.d[l * 4 + 1] = {ew2 + (size_t)l * 64 * 64,  E2H[l], E2L[l], 64};
        pack.d[l * 4 + 2] = {nw1 + (size_t)l * 128 * 64, NH[l],  NL[l],  128};
        pack.d[l * 4 + 3] = {nw2 + (size_t)l * 64 * 64,  N2H[l], N2L[l], 64};
    }
    conv_weights<<<dim3(48, 8), 256, 0, stream>>>(pack);

    const int egrid = (E + 63) / 64;
    const int ngrid = (N + 63) / 64;
    const size_t aggBytes = (size_t)N * H * sizeof(float);

    for (int l = 0; l < 2; ++l) {
        const float* xin  = (l == 0) ? x0  : outX;
        const float* eain = (l == 0) ? ea0 : outE;
        hipMemsetAsync(agg, 0, aggBytes, stream);
        gnn_edge_mfma<<<egrid, 256, 0, stream>>>(
            xin, eain, outE, srcI, dstI,
            EH[l], EL[l], eb1 + l * H,
            E2H[l], E2L[l], eb2 + l * H,
            agg, E);
        gnn_node_mfma<<<ngrid, 256, 0, stream>>>(
            xin, agg, outX,
            NH[l], NL[l], nb1 + l * H,
            N2H[l], N2L[l], nb2 + l * H,
            N);
    }
}